// Round 9
// baseline (805.719 us; speedup 1.0000x reference)
//
#include <hip/hip_runtime.h>
#include <hip/hip_bf16.h>

// GCN encoder, reassociated:  out = Y4^T · emb[x] · W^4 + bias terms,
// where Y4 = (A^T)^4 S (S = one-hot columns of the 64 selected nodes).
// R6 lesson: zacc was latency-bound (VALU 4%, HBM 1.4%, occ 21%).
// R9 (two disjoint-kernel experiments, per-kernel attribution via rocprof):
//   (a) zacc unroll-8 ILP + grid 250x4 (31 waves/CU)   [carried from R7, unmeasured]
//   (b) spmm unroll-4 (2->4 independent gather chains)  [new]

#define D 128
#define NG 64   // graphs in batch (B)

// ---- fused degree histograms: degd (by dst, for norm), degs (by src, for CSR) ----
__global__ void hist2_kernel(const int* __restrict__ src, const int* __restrict__ dst,
                             int* __restrict__ degd, int* __restrict__ degs, int E) {
    int e = blockIdx.x * blockDim.x + threadIdx.x;
    if (e < E) { atomicAdd(&degd[dst[e]], 1); atomicAdd(&degs[src[e]], 1); }
}

// ---- deg_inv_sqrt (GCN norm uses in-degree by dst) ----
__global__ void dis_kernel(const int* __restrict__ degd, float* __restrict__ dis, int n) {
    int i = blockIdx.x * blockDim.x + threadIdx.x;
    if (i < n) {
        int d = degd[i];
        dis[i] = (d > 0) ? rsqrtf((float)d) : 0.0f;
    }
}

__device__ __forceinline__ int wave_incl_scan(int v, int lane) {
    #pragma unroll
    for (int off = 1; off < 64; off <<= 1) {
        int t = __shfl_up(v, off);
        if (lane >= off) v += t;
    }
    return v;
}

// ---- 3-stage exclusive scan of degs -> srow_ptr ----
__global__ __launch_bounds__(256) void scan_reduce(const int* __restrict__ deg,
                                                   int* __restrict__ bsum, int n) {
    __shared__ int wsum[4];
    int b = blockIdx.x, tid = threadIdx.x;
    int s = 0;
    for (int j = tid; j < 1024; j += 256) {
        int idx = b * 1024 + j;
        if (idx < n) s += deg[idx];
    }
    #pragma unroll
    for (int off = 32; off; off >>= 1) s += __shfl_down(s, off);
    int lane = tid & 63, wid = tid >> 6;
    if (lane == 0) wsum[wid] = s;
    __syncthreads();
    if (tid == 0) bsum[b] = wsum[0] + wsum[1] + wsum[2] + wsum[3];
}

__global__ void scan_bsum(const int* __restrict__ bsum, int* __restrict__ boff, int nb) {
    __shared__ int buf[1024];
    int tid = threadIdx.x;
    int v = (tid < nb) ? bsum[tid] : 0;
    buf[tid] = v;
    __syncthreads();
    for (int off = 1; off < 1024; off <<= 1) {
        int t = (tid >= off) ? buf[tid - off] : 0;
        __syncthreads();
        buf[tid] += t;
        __syncthreads();
    }
    if (tid < nb) boff[tid] = buf[tid] - v;
}

__global__ __launch_bounds__(256) void scan_final(const int* __restrict__ deg,
                                                  const int* __restrict__ boff,
                                                  int* __restrict__ row_ptr, int n) {
    __shared__ int wsum[4];
    int b = blockIdx.x, tid = threadIdx.x;
    int lane = tid & 63, wid = tid >> 6;
    int base = b * 1024 + tid * 4;
    int v[4], s = 0;
    #pragma unroll
    for (int j = 0; j < 4; j++) {
        int idx = base + j;
        v[j] = (idx < n) ? deg[idx] : 0;
        s += v[j];
    }
    int incl = wave_incl_scan(s, lane);
    if (lane == 63) wsum[wid] = incl;
    __syncthreads();
    int woff = 0;
    for (int w = 0; w < wid; w++) woff += wsum[w];
    int run = incl - s + woff + boff[b];
    #pragma unroll
    for (int j = 0; j < 4; j++) {
        int idx = base + j;
        run += v[j];
        if (idx < n) row_ptr[idx + 1] = run;
    }
    if (b == 0 && tid == 0) row_ptr[0] = 0;
}

// ---- CSR by SRC (for A^T application); neighbor = dst, weight = dis[src]*dis[dst] ----
__global__ void fill_csr_kernel(const int* __restrict__ src, const int* __restrict__ dst,
                                const float* __restrict__ dis, const int* __restrict__ srow,
                                int* __restrict__ cnt, int* __restrict__ scol,
                                float* __restrict__ senorm, int E) {
    int e = blockIdx.x * blockDim.x + threadIdx.x;
    if (e >= E) return;
    int s = src[e], d = dst[e];
    int pos = srow[s] + atomicAdd(&cnt[s], 1);
    scol[pos] = d;
    senorm[pos] = dis[s] * dis[d];
}

// ---- Y0 init: Y[sel_g, g] = 1 (auto-detect int32/int64 ptr) ----
__global__ void yinit_kernel(const int* __restrict__ ptr32, float* __restrict__ Y) {
    int g = threadIdx.x;   // one block of NG threads
    bool is64 = (ptr32[3] == 0);   // hi word of ptr[1] is 0 iff int64 (ptr[1] > 0)
    long long node;
    if (is64) node = ((const long long*)ptr32)[g + 1] - 1;
    else      node = (long long)ptr32[g + 1] - 1;
    Y[node * NG + g] = 1.0f;
}

// ---- Y_{k+1}[u,:] = sum_{e: src=u} norm_e * Y_k[dst_e,:]
// R9: 4-edge unroll — 4 independent scol->Y gather chains in flight (was 2). ----
__global__ __launch_bounds__(256) void spmm_kernel(const float* __restrict__ Yin,
                                                   const int* __restrict__ srow,
                                                   const int* __restrict__ scol,
                                                   const float* __restrict__ senorm,
                                                   float* __restrict__ Yout, int n) {
    int node = (blockIdx.x * blockDim.x + threadIdx.x) >> 6;
    int g = threadIdx.x & 63;
    if (node >= n) return;
    int beg = srow[node], end = srow[node + 1];
    float a0 = 0.f, a1 = 0.f, a2 = 0.f, a3 = 0.f;
    int j = beg;
    for (; j + 3 < end; j += 4) {
        int s0 = scol[j], s1 = scol[j + 1], s2 = scol[j + 2], s3 = scol[j + 3];
        float w0 = senorm[j], w1 = senorm[j + 1], w2 = senorm[j + 2], w3 = senorm[j + 3];
        a0 += Yin[(size_t)s0 * NG + g] * w0;
        a1 += Yin[(size_t)s1 * NG + g] * w1;
        a2 += Yin[(size_t)s2 * NG + g] * w2;
        a3 += Yin[(size_t)s3 * NG + g] * w3;
    }
    for (; j < end; j++) a0 += Yin[(size_t)scol[j] * NG + g] * senorm[j];
    Yout[(size_t)node * NG + g] = (a0 + a1) + (a2 + a3);
}

// ---- cs[g] += sum_i Y[i,g]  (= A^k 1 at selected nodes) ----
__global__ __launch_bounds__(256) void colsum_kernel(const float* __restrict__ Y,
                                                     float* __restrict__ cs, int n) {
    __shared__ float part[4][64];
    int g = threadIdx.x & 63, w = threadIdx.x >> 6;
    float a = 0.f;
    for (int i = blockIdx.x * 4 + w; i < n; i += gridDim.x * 4)
        a += Y[(size_t)i * NG + g];
    part[w][g] = a;
    __syncthreads();
    if (w == 0) atomicAdd(&cs[g], part[0][g] + part[1][g] + part[2][g] + part[3][g]);
}

// ---- Z[g,d] = sum_i Y4[i,g] * emb[x[i], d]
// R7: unroll-8 — 2x int4 token loads + 8 Y + 8 emb float4 all independent/in-flight;
// 4 independent FMA chains (acc.x/y/z/w). grid (250 chunks x 4 d-slices), block 512,
// chunk multiple of 8 so the unrolled body needs no bounds checks (tail loop for generic N).
__global__ __launch_bounds__(512, 8) void zacc_kernel(const float* __restrict__ Y,
                                                      const int* __restrict__ x,
                                                      const float* __restrict__ emb,
                                                      float* __restrict__ Z, int n) {
    int g = threadIdx.x & 63, d8 = threadIdx.x >> 6;
    int dbase = blockIdx.y * 32 + d8 * 4;
    const float4* emb4 = (const float4*)emb;
    int q = dbase >> 2;                      // float4 index within emb row
    float4 acc = {0.f, 0.f, 0.f, 0.f};
    int chunk = ((n + gridDim.x - 1) / gridDim.x + 7) & ~7;   // multiple of 8
    int i0 = blockIdx.x * chunk;
    int i1 = min(n, i0 + chunk);
    int i = i0;
    for (; i + 8 <= i1; i += 8) {
        int4 xa = *(const int4*)(x + i);         // 32B-aligned (i multiple of 8)
        int4 xb = *(const int4*)(x + i + 4);
        float y0 = Y[(size_t)(i + 0) * NG + g];
        float y1 = Y[(size_t)(i + 1) * NG + g];
        float y2 = Y[(size_t)(i + 2) * NG + g];
        float y3 = Y[(size_t)(i + 3) * NG + g];
        float y4 = Y[(size_t)(i + 4) * NG + g];
        float y5 = Y[(size_t)(i + 5) * NG + g];
        float y6 = Y[(size_t)(i + 6) * NG + g];
        float y7 = Y[(size_t)(i + 7) * NG + g];
        float4 v0 = emb4[(size_t)xa.x * 32 + q];
        float4 v1 = emb4[(size_t)xa.y * 32 + q];
        float4 v2 = emb4[(size_t)xa.z * 32 + q];
        float4 v3 = emb4[(size_t)xa.w * 32 + q];
        float4 v4 = emb4[(size_t)xb.x * 32 + q];
        float4 v5 = emb4[(size_t)xb.y * 32 + q];
        float4 v6 = emb4[(size_t)xb.z * 32 + q];
        float4 v7 = emb4[(size_t)xb.w * 32 + q];
        acc.x += y0 * v0.x; acc.y += y0 * v0.y; acc.z += y0 * v0.z; acc.w += y0 * v0.w;
        acc.x += y1 * v1.x; acc.y += y1 * v1.y; acc.z += y1 * v1.z; acc.w += y1 * v1.w;
        acc.x += y2 * v2.x; acc.y += y2 * v2.y; acc.z += y2 * v2.z; acc.w += y2 * v2.w;
        acc.x += y3 * v3.x; acc.y += y3 * v3.y; acc.z += y3 * v3.z; acc.w += y3 * v3.w;
        acc.x += y4 * v4.x; acc.y += y4 * v4.y; acc.z += y4 * v4.z; acc.w += y4 * v4.w;
        acc.x += y5 * v5.x; acc.y += y5 * v5.y; acc.z += y5 * v5.z; acc.w += y5 * v5.w;
        acc.x += y6 * v6.x; acc.y += y6 * v6.y; acc.z += y6 * v6.z; acc.w += y6 * v6.w;
        acc.x += y7 * v7.x; acc.y += y7 * v7.y; acc.z += y7 * v7.z; acc.w += y7 * v7.w;
    }
    for (; i < i1; i++) {                        // tail (generic N only)
        int tok = x[i];
        float y = Y[(size_t)i * NG + g];
        float4 v = emb4[(size_t)tok * 32 + q];
        acc.x += y * v.x; acc.y += y * v.y; acc.z += y * v.z; acc.w += y * v.w;
    }
    float* zp = Z + g * D + dbase;
    atomicAdd(zp + 0, acc.x);
    atomicAdd(zp + 1, acc.y);
    atomicAdd(zp + 2, acc.z);
    atomicAdd(zp + 3, acc.w);
}

// ---- C = A*A for 128x128 (grid 16, block computes 8 rows; A staged in LDS) ----
__global__ __launch_bounds__(256) void matsq_kernel(const float* __restrict__ A,
                                                    float* __restrict__ C) {
    __shared__ float Al[D * D];
    int tid = threadIdx.x;
    const float4* A4 = (const float4*)A;
    float4* Al4 = (float4*)Al;
    for (int i = tid; i < D * D / 4; i += 256) Al4[i] = A4[i];
    __syncthreads();
    int r = blockIdx.x * 8 + (tid >> 5);
    int c0 = (tid & 31) * 4;
    float4 acc = {0.f, 0.f, 0.f, 0.f};
    for (int k = 0; k < D; k++) {
        float a = Al[r * D + k];
        float4 w = *(const float4*)&Al[k * D + c0];
        acc.x += a * w.x; acc.y += a * w.y; acc.z += a * w.z; acc.w += a * w.w;
    }
    *(float4*)&C[r * D + c0] = acc;
}

// ---- T[k] = b^T W^{k+1}, k=0..2 (one block, 128 threads) ----
__global__ void tvec_kernel(const float* __restrict__ b, const float* __restrict__ W,
                            float* __restrict__ T) {
    __shared__ float cur[D];
    int tid = threadIdx.x;
    cur[tid] = b[tid];
    __syncthreads();
    for (int it = 0; it < 3; it++) {
        float acc = 0.f;
        for (int k = 0; k < D; k++) acc += cur[k] * W[k * D + tid];
        __syncthreads();
        cur[tid] = acc;
        T[it * D + tid] = acc;
        __syncthreads();
    }
}

// ---- out[g,d] = (Z*W4)[g,d] + cs1[g]*T1[d] + cs2[g]*T2[d] + cs3[g]*T3[d] + b[d] ----
__global__ __launch_bounds__(256) void final_kernel(const float* __restrict__ Z,
                                                    const float* __restrict__ W4,
                                                    const float* __restrict__ T,
                                                    const float* __restrict__ cs,
                                                    const float* __restrict__ b,
                                                    float* __restrict__ out) {
    int o = blockIdx.x * blockDim.x + threadIdx.x;
    if (o >= NG * D) return;
    int g = o >> 7, d = o & (D - 1);
    float acc = b[d];
    for (int k = 0; k < D; k++) acc += Z[g * D + k] * W4[k * D + d];
    acc += cs[g] * T[d] + cs[64 + g] * T[D + d] + cs[128 + g] * T[2 * D + d];
    out[o] = acc;
}

extern "C" void kernel_launch(void* const* d_in, const int* in_sizes, int n_in,
                              void* d_out, int out_size, void* d_ws, size_t ws_size,
                              hipStream_t stream) {
    const int*   x    = (const int*)d_in[0];
    const int*   ei   = (const int*)d_in[1];
    const int*   ptr  = (const int*)d_in[2];   // width auto-detected on device
    const float* emb  = (const float*)d_in[4];
    const float* W    = (const float*)d_in[5];
    const float* bias = (const float*)d_in[6];

    const int N = in_sizes[0];
    const int E = in_sizes[1] / 2;

    const int* src = ei;
    const int* dst = ei + E;

    char* ws = (char*)d_ws;
    size_t off = 0;
    auto carve = [&](size_t bytes) -> void* {
        void* p = ws + off;
        off += (bytes + 255) & ~(size_t)255;
        return p;
    };
    float* Ya     = (float*)carve((size_t)N * NG * 4);
    float* Yb     = (float*)carve((size_t)N * NG * 4);
    int*   degd   = (int*)  carve((size_t)N * 4 * 2);   // degd + degs adjacent (one memset)
    int*   degs   = degd + N;
    float* dis    = (float*)carve((size_t)N * 4);
    int*   srow   = (int*)  carve((size_t)(N + 1) * 4);
    int*   cnt    = (int*)  carve((size_t)N * 4);
    int*   scol   = (int*)  carve((size_t)E * 4);
    float* senorm = (float*)carve((size_t)E * 4);
    int    nb     = (N + 1023) / 1024;
    int*   bsum   = (int*)  carve((size_t)nb * 4);
    int*   boff   = (int*)  carve((size_t)nb * 4);
    float* Z      = (float*)carve((size_t)NG * D * 4);  // 32768 B (256-aligned)
    float* cs     = (float*)carve((size_t)3 * NG * 4);  // adjacent to Z
    float* W2     = (float*)carve((size_t)D * D * 4);
    float* W4     = (float*)carve((size_t)D * D * 4);
    float* T      = (float*)carve((size_t)3 * D * 4);

    hipMemsetAsync(degd, 0, (size_t)N * 4 * 2, stream);
    hipMemsetAsync(cnt,  0, (size_t)N * 4, stream);
    hipMemsetAsync(Ya,   0, (size_t)N * NG * 4, stream);
    hipMemsetAsync(Z,    0, (size_t)(NG * D + 3 * NG) * 4, stream);  // Z + cs contiguous

    hist2_kernel<<<(E + 255) / 256, 256, 0, stream>>>(src, dst, degd, degs, E);
    dis_kernel<<<(N + 255) / 256, 256, 0, stream>>>(degd, dis, N);
    scan_reduce<<<nb, 256, 0, stream>>>(degs, bsum, N);
    scan_bsum<<<1, 1024, 0, stream>>>(bsum, boff, nb);
    scan_final<<<nb, 256, 0, stream>>>(degs, boff, srow, N);
    fill_csr_kernel<<<(E + 255) / 256, 256, 0, stream>>>(src, dst, dis, srow, cnt,
                                                         scol, senorm, E);
    yinit_kernel<<<1, NG, 0, stream>>>(ptr, Ya);

    int sg = (N * 64 + 255) / 256;
    spmm_kernel<<<sg, 256, 0, stream>>>(Ya, srow, scol, senorm, Yb, N);   // Y1
    colsum_kernel<<<64, 256, 0, stream>>>(Yb, cs + 0, N);
    spmm_kernel<<<sg, 256, 0, stream>>>(Yb, srow, scol, senorm, Ya, N);   // Y2
    colsum_kernel<<<64, 256, 0, stream>>>(Ya, cs + 64, N);
    spmm_kernel<<<sg, 256, 0, stream>>>(Ya, srow, scol, senorm, Yb, N);   // Y3
    colsum_kernel<<<64, 256, 0, stream>>>(Yb, cs + 128, N);
    spmm_kernel<<<sg, 256, 0, stream>>>(Yb, srow, scol, senorm, Ya, N);   // Y4

    matsq_kernel<<<16, 256, 0, stream>>>(W, W2);
    matsq_kernel<<<16, 256, 0, stream>>>(W2, W4);
    tvec_kernel<<<1, D, 0, stream>>>(bias, W, T);

    dim3 zgrid(250, 4);
    zacc_kernel<<<zgrid, 512, 0, stream>>>(Ya, x, emb, Z, N);
    final_kernel<<<(NG * D + 255) / 256, 256, 0, stream>>>(Z, W4, T, cs, bias,
                                                           (float*)d_out);
}

// Round 14
// 563.747 us; speedup vs baseline: 1.4292x; 1.4292x over previous
//
#include <hip/hip_runtime.h>
#include <hip/hip_bf16.h>

// GCN encoder, reassociated:  out = Y4^T · emb[x] · W^4 + bias terms.
// R9 lesson: zacc was VMEM-issue-bound (8x/64x redundant loads) + cross-XCD atomic
// contention (64MB WRITE for 32KB output). R10-R14 (resubmits, infra timeouts):
// zacc v3 = LDS-staged rank-1 GEMM (stage Y-tile + gathered emb-tile once, broadcast
// from LDS), private per-block partials + zreduce (no atomics). spmm unroll-4 kept.

#define D 128
#define NG 64     // graphs in batch (B)
#define ZTILE 32  // i's per LDS tile in zacc
#define ZCHUNK 224 // i's per zacc block (7 tiles)

// ---- fused degree histograms: degd (by dst, for norm), degs (by src, for CSR) ----
__global__ void hist2_kernel(const int* __restrict__ src, const int* __restrict__ dst,
                             int* __restrict__ degd, int* __restrict__ degs, int E) {
    int e = blockIdx.x * blockDim.x + threadIdx.x;
    if (e < E) { atomicAdd(&degd[dst[e]], 1); atomicAdd(&degs[src[e]], 1); }
}

// ---- deg_inv_sqrt (GCN norm uses in-degree by dst) ----
__global__ void dis_kernel(const int* __restrict__ degd, float* __restrict__ dis, int n) {
    int i = blockIdx.x * blockDim.x + threadIdx.x;
    if (i < n) {
        int d = degd[i];
        dis[i] = (d > 0) ? rsqrtf((float)d) : 0.0f;
    }
}

__device__ __forceinline__ int wave_incl_scan(int v, int lane) {
    #pragma unroll
    for (int off = 1; off < 64; off <<= 1) {
        int t = __shfl_up(v, off);
        if (lane >= off) v += t;
    }
    return v;
}

// ---- 3-stage exclusive scan of degs -> srow_ptr ----
__global__ __launch_bounds__(256) void scan_reduce(const int* __restrict__ deg,
                                                   int* __restrict__ bsum, int n) {
    __shared__ int wsum[4];
    int b = blockIdx.x, tid = threadIdx.x;
    int s = 0;
    for (int j = tid; j < 1024; j += 256) {
        int idx = b * 1024 + j;
        if (idx < n) s += deg[idx];
    }
    #pragma unroll
    for (int off = 32; off; off >>= 1) s += __shfl_down(s, off);
    int lane = tid & 63, wid = tid >> 6;
    if (lane == 0) wsum[wid] = s;
    __syncthreads();
    if (tid == 0) bsum[b] = wsum[0] + wsum[1] + wsum[2] + wsum[3];
}

__global__ void scan_bsum(const int* __restrict__ bsum, int* __restrict__ boff, int nb) {
    __shared__ int buf[1024];
    int tid = threadIdx.x;
    int v = (tid < nb) ? bsum[tid] : 0;
    buf[tid] = v;
    __syncthreads();
    for (int off = 1; off < 1024; off <<= 1) {
        int t = (tid >= off) ? buf[tid - off] : 0;
        __syncthreads();
        buf[tid] += t;
        __syncthreads();
    }
    if (tid < nb) boff[tid] = buf[tid] - v;
}

__global__ __launch_bounds__(256) void scan_final(const int* __restrict__ deg,
                                                  const int* __restrict__ boff,
                                                  int* __restrict__ row_ptr, int n) {
    __shared__ int wsum[4];
    int b = blockIdx.x, tid = threadIdx.x;
    int lane = tid & 63, wid = tid >> 6;
    int base = b * 1024 + tid * 4;
    int v[4], s = 0;
    #pragma unroll
    for (int j = 0; j < 4; j++) {
        int idx = base + j;
        v[j] = (idx < n) ? deg[idx] : 0;
        s += v[j];
    }
    int incl = wave_incl_scan(s, lane);
    if (lane == 63) wsum[wid] = incl;
    __syncthreads();
    int woff = 0;
    for (int w = 0; w < wid; w++) woff += wsum[w];
    int run = incl - s + woff + boff[b];
    #pragma unroll
    for (int j = 0; j < 4; j++) {
        int idx = base + j;
        run += v[j];
        if (idx < n) row_ptr[idx + 1] = run;
    }
    if (b == 0 && tid == 0) row_ptr[0] = 0;
}

// ---- CSR by SRC (for A^T application); neighbor = dst, weight = dis[src]*dis[dst] ----
__global__ void fill_csr_kernel(const int* __restrict__ src, const int* __restrict__ dst,
                                const float* __restrict__ dis, const int* __restrict__ srow,
                                int* __restrict__ cnt, int* __restrict__ scol,
                                float* __restrict__ senorm, int E) {
    int e = blockIdx.x * blockDim.x + threadIdx.x;
    if (e >= E) return;
    int s = src[e], d = dst[e];
    int pos = srow[s] + atomicAdd(&cnt[s], 1);
    scol[pos] = d;
    senorm[pos] = dis[s] * dis[d];
}

// ---- Y0 init: Y[sel_g, g] = 1 (auto-detect int32/int64 ptr) ----
__global__ void yinit_kernel(const int* __restrict__ ptr32, float* __restrict__ Y) {
    int g = threadIdx.x;   // one block of NG threads
    bool is64 = (ptr32[3] == 0);   // hi word of ptr[1] is 0 iff int64 (ptr[1] > 0)
    long long node;
    if (is64) node = ((const long long*)ptr32)[g + 1] - 1;
    else      node = (long long)ptr32[g + 1] - 1;
    Y[node * NG + g] = 1.0f;
}

// ---- Y_{k+1}[u,:] = sum_{e: src=u} norm_e * Y_k[dst_e,:]  (wave/node, 4-chain unroll) ----
__global__ __launch_bounds__(256) void spmm_kernel(const float* __restrict__ Yin,
                                                   const int* __restrict__ srow,
                                                   const int* __restrict__ scol,
                                                   const float* __restrict__ senorm,
                                                   float* __restrict__ Yout, int n) {
    int node = (blockIdx.x * blockDim.x + threadIdx.x) >> 6;
    int g = threadIdx.x & 63;
    if (node >= n) return;
    int beg = srow[node], end = srow[node + 1];
    float a0 = 0.f, a1 = 0.f, a2 = 0.f, a3 = 0.f;
    int j = beg;
    for (; j + 3 < end; j += 4) {
        int s0 = scol[j], s1 = scol[j + 1], s2 = scol[j + 2], s3 = scol[j + 3];
        float w0 = senorm[j], w1 = senorm[j + 1], w2 = senorm[j + 2], w3 = senorm[j + 3];
        a0 += Yin[(size_t)s0 * NG + g] * w0;
        a1 += Yin[(size_t)s1 * NG + g] * w1;
        a2 += Yin[(size_t)s2 * NG + g] * w2;
        a3 += Yin[(size_t)s3 * NG + g] * w3;
    }
    for (; j < end; j++) a0 += Yin[(size_t)scol[j] * NG + g] * senorm[j];
    Yout[(size_t)node * NG + g] = (a0 + a1) + (a2 + a3);
}

// ---- cs[g] += sum_i Y[i,g]  (= A^k 1 at selected nodes) ----
__global__ __launch_bounds__(256) void colsum_kernel(const float* __restrict__ Y,
                                                     float* __restrict__ cs, int n) {
    __shared__ float part[4][64];
    int g = threadIdx.x & 63, w = threadIdx.x >> 6;
    float a = 0.f;
    for (int i = blockIdx.x * 4 + w; i < n; i += gridDim.x * 4)
        a += Y[(size_t)i * NG + g];
    part[w][g] = a;
    __syncthreads();
    if (w == 0) atomicAdd(&cs[g], part[0][g] + part[1][g] + part[2][g] + part[3][g]);
}

// ---- zacc v3: Zp[b][g][d] = sum_{i in chunk b} Y[i,g] * emb[x[i],d]
// LDS-staged rank-1 updates: per 32-i tile, stage Y-tile (8KB, coalesced) and
// gathered emb rows (16KB) once; 512 threads = (g, d8) each hold 4 named float4
// accs (static regs) and read LDS via broadcast. No atomics: private partials. ----
__global__ __launch_bounds__(512, 4) void zacc_kernel(const float* __restrict__ Y,
                                                      const int* __restrict__ x,
                                                      const float* __restrict__ emb,
                                                      float* __restrict__ Zp, int n) {
    __shared__ float Yl[ZTILE * NG];        // 8 KB
    __shared__ float embl[ZTILE * D];       // 16 KB
    const float4* Y4 = (const float4*)Y;
    const float4* emb4 = (const float4*)emb;
    float4* Yl4 = (float4*)Yl;
    float4* embl4 = (float4*)embl;
    int tid = threadIdx.x;
    int g = tid & 63, d8 = tid >> 6;
    int i0 = blockIdx.x * ZCHUNK;
    float4 a0 = {0,0,0,0}, a1 = {0,0,0,0}, a2 = {0,0,0,0}, a3 = {0,0,0,0};
    for (int t = 0; t < ZCHUNK / ZTILE; t++) {
        int ib = i0 + t * ZTILE;
        // stage: thread -> (si = tid>>4, q = tid&15)
        int si = tid >> 4, q = tid & 15;
        int gi = ib + si;
        bool ok = (gi < n);
        float4 z4 = {0,0,0,0};
        Yl4[si * 16 + q] = ok ? Y4[(size_t)gi * 16 + q] : z4;     // coalesced: addr==tid
        int tok = ok ? x[gi] : 0;                                  // 16-thread broadcast
        embl4[si * 32 + q]      = emb4[(size_t)tok * 32 + q];      // 256B-chunk gather
        embl4[si * 32 + q + 16] = emb4[(size_t)tok * 32 + q + 16];
        __syncthreads();
        #pragma unroll 4
        for (int ii = 0; ii < ZTILE; ii++) {
            float y = Yl[ii * NG + g];                 // 2-way bank (free) / broadcast
            float4 e0 = embl4[ii * 32 + d8 * 4 + 0];   // wave-uniform -> broadcast
            float4 e1 = embl4[ii * 32 + d8 * 4 + 1];
            float4 e2 = embl4[ii * 32 + d8 * 4 + 2];
            float4 e3 = embl4[ii * 32 + d8 * 4 + 3];
            a0.x += y * e0.x; a0.y += y * e0.y; a0.z += y * e0.z; a0.w += y * e0.w;
            a1.x += y * e1.x; a1.y += y * e1.y; a1.z += y * e1.z; a1.w += y * e1.w;
            a2.x += y * e2.x; a2.y += y * e2.y; a2.z += y * e2.z; a2.w += y * e2.w;
            a3.x += y * e3.x; a3.y += y * e3.y; a3.z += y * e3.z; a3.w += y * e3.w;
        }
        __syncthreads();
    }
    float4* zp = (float4*)(Zp + (size_t)blockIdx.x * NG * D + g * D + d8 * 16);
    zp[0] = a0; zp[1] = a1; zp[2] = a2; zp[3] = a3;
}

// ---- Z[o] = sum_b Zp[b][o] ----
__global__ __launch_bounds__(256) void zreduce_kernel(const float* __restrict__ Zp,
                                                      float* __restrict__ Z, int nzb) {
    int o = blockIdx.x * blockDim.x + threadIdx.x;   // o < NG*D
    float a = 0.f;
    for (int b = 0; b < nzb; b++) a += Zp[(size_t)b * NG * D + o];
    Z[o] = a;
}

// ---- C = A*A for 128x128 (grid 16, block computes 8 rows; A staged in LDS) ----
__global__ __launch_bounds__(256) void matsq_kernel(const float* __restrict__ A,
                                                    float* __restrict__ C) {
    __shared__ float Al[D * D];
    int tid = threadIdx.x;
    const float4* A4 = (const float4*)A;
    float4* Al4 = (float4*)Al;
    for (int i = tid; i < D * D / 4; i += 256) Al4[i] = A4[i];
    __syncthreads();
    int r = blockIdx.x * 8 + (tid >> 5);
    int c0 = (tid & 31) * 4;
    float4 acc = {0.f, 0.f, 0.f, 0.f};
    for (int k = 0; k < D; k++) {
        float a = Al[r * D + k];
        float4 w = *(const float4*)&Al[k * D + c0];
        acc.x += a * w.x; acc.y += a * w.y; acc.z += a * w.z; acc.w += a * w.w;
    }
    *(float4*)&C[r * D + c0] = acc;
}

// ---- T[k] = b^T W^{k+1}, k=0..2 (one block, 128 threads) ----
__global__ void tvec_kernel(const float* __restrict__ b, const float* __restrict__ W,
                            float* __restrict__ T) {
    __shared__ float cur[D];
    int tid = threadIdx.x;
    cur[tid] = b[tid];
    __syncthreads();
    for (int it = 0; it < 3; it++) {
        float acc = 0.f;
        for (int k = 0; k < D; k++) acc += cur[k] * W[k * D + tid];
        __syncthreads();
        cur[tid] = acc;
        T[it * D + tid] = acc;
        __syncthreads();
    }
}

// ---- out[g,d] = (Z*W4)[g,d] + cs1[g]*T1[d] + cs2[g]*T2[d] + cs3[g]*T3[d] + b[d] ----
__global__ __launch_bounds__(256) void final_kernel(const float* __restrict__ Z,
                                                    const float* __restrict__ W4,
                                                    const float* __restrict__ T,
                                                    const float* __restrict__ cs,
                                                    const float* __restrict__ b,
                                                    float* __restrict__ out) {
    int o = blockIdx.x * blockDim.x + threadIdx.x;
    if (o >= NG * D) return;
    int g = o >> 7, d = o & (D - 1);
    float acc = b[d];
    for (int k = 0; k < D; k++) acc += Z[g * D + k] * W4[k * D + d];
    acc += cs[g] * T[d] + cs[64 + g] * T[D + d] + cs[128 + g] * T[2 * D + d];
    out[o] = acc;
}

extern "C" void kernel_launch(void* const* d_in, const int* in_sizes, int n_in,
                              void* d_out, int out_size, void* d_ws, size_t ws_size,
                              hipStream_t stream) {
    const int*   x    = (const int*)d_in[0];
    const int*   ei   = (const int*)d_in[1];
    const int*   ptr  = (const int*)d_in[2];   // width auto-detected on device
    const float* emb  = (const float*)d_in[4];
    const float* W    = (const float*)d_in[5];
    const float* bias = (const float*)d_in[6];

    const int N = in_sizes[0];
    const int E = in_sizes[1] / 2;

    const int* src = ei;
    const int* dst = ei + E;

    char* ws = (char*)d_ws;
    size_t off = 0;
    auto carve = [&](size_t bytes) -> void* {
        void* p = ws + off;
        off += (bytes + 255) & ~(size_t)255;
        return p;
    };
    float* Ya     = (float*)carve((size_t)N * NG * 4);
    float* Yb     = (float*)carve((size_t)N * NG * 4);
    int*   degd   = (int*)  carve((size_t)N * 4 * 2);   // degd + degs adjacent (one memset)
    int*   degs   = degd + N;
    float* dis    = (float*)carve((size_t)N * 4);
    int*   srow   = (int*)  carve((size_t)(N + 1) * 4);
    int*   cnt    = (int*)  carve((size_t)N * 4);
    int*   scol   = (int*)  carve((size_t)E * 4);
    float* senorm = (float*)carve((size_t)E * 4);
    int    nb     = (N + 1023) / 1024;
    int*   bsum   = (int*)  carve((size_t)nb * 4);
    int*   boff   = (int*)  carve((size_t)nb * 4);
    float* Z      = (float*)carve((size_t)NG * D * 4);
    float* cs     = (float*)carve((size_t)3 * NG * 4);
    float* W2     = (float*)carve((size_t)D * D * 4);
    float* W4     = (float*)carve((size_t)D * D * 4);
    float* T      = (float*)carve((size_t)3 * D * 4);
    int    nzb    = (N + ZCHUNK - 1) / ZCHUNK;
    float* Zp     = (float*)carve((size_t)nzb * NG * D * 4);  // ~7.3 MB partials

    hipMemsetAsync(degd, 0, (size_t)N * 4 * 2, stream);
    hipMemsetAsync(cnt,  0, (size_t)N * 4, stream);
    hipMemsetAsync(Ya,   0, (size_t)N * NG * 4, stream);
    hipMemsetAsync(cs,   0, (size_t)3 * NG * 4, stream);

    hist2_kernel<<<(E + 255) / 256, 256, 0, stream>>>(src, dst, degd, degs, E);
    dis_kernel<<<(N + 255) / 256, 256, 0, stream>>>(degd, dis, N);
    scan_reduce<<<nb, 256, 0, stream>>>(degs, bsum, N);
    scan_bsum<<<1, 1024, 0, stream>>>(bsum, boff, nb);
    scan_final<<<nb, 256, 0, stream>>>(degs, boff, srow, N);
    fill_csr_kernel<<<(E + 255) / 256, 256, 0, stream>>>(src, dst, dis, srow, cnt,
                                                         scol, senorm, E);
    yinit_kernel<<<1, NG, 0, stream>>>(ptr, Ya);

    int sg = (N * 64 + 255) / 256;
    spmm_kernel<<<sg, 256, 0, stream>>>(Ya, srow, scol, senorm, Yb, N);   // Y1
    colsum_kernel<<<64, 256, 0, stream>>>(Yb, cs + 0, N);
    spmm_kernel<<<sg, 256, 0, stream>>>(Yb, srow, scol, senorm, Ya, N);   // Y2
    colsum_kernel<<<64, 256, 0, stream>>>(Ya, cs + 64, N);
    spmm_kernel<<<sg, 256, 0, stream>>>(Ya, srow, scol, senorm, Yb, N);   // Y3
    colsum_kernel<<<64, 256, 0, stream>>>(Yb, cs + 128, N);
    spmm_kernel<<<sg, 256, 0, stream>>>(Yb, srow, scol, senorm, Ya, N);   // Y4

    matsq_kernel<<<16, 256, 0, stream>>>(W, W2);
    matsq_kernel<<<16, 256, 0, stream>>>(W2, W4);
    tvec_kernel<<<1, D, 0, stream>>>(bias, W, T);

    zacc_kernel<<<nzb, 512, 0, stream>>>(Ya, x, emb, Zp, N);
    zreduce_kernel<<<(NG * D + 255) / 256, 256, 0, stream>>>(Zp, Z, nzb);
    final_kernel<<<(NG * D + 255) / 256, 256, 0, stream>>>(Z, W4, T, cs, bias,
                                                           (float*)d_out);
}

// Round 15
// 502.732 us; speedup vs baseline: 1.6027x; 1.1214x over previous
//
#include <hip/hip_runtime.h>
#include <hip/hip_bf16.h>

// GCN encoder, reassociated:  out = Y4^T · emb[x] · W^4 + bias terms.
// R14: zacc v3 landed (338us -> off top-5; total 806->564). New top: zreduce 65us at
// 1% occupancy (32 blocks, serial 224-partial walk) — same tiny-grid latency mistake
// as R1 scan / R6 zacc. R15: zreduce v2 = 2D grid (32 o-chunks x 8 b-slices), 28
// partials/block, one atomicAdd per (o,slice). Nothing else touched.

#define D 128
#define NG 64     // graphs in batch (B)
#define ZTILE 32  // i's per LDS tile in zacc
#define ZCHUNK 224 // i's per zacc block (7 tiles)

// ---- fused degree histograms: degd (by dst, for norm), degs (by src, for CSR) ----
__global__ void hist2_kernel(const int* __restrict__ src, const int* __restrict__ dst,
                             int* __restrict__ degd, int* __restrict__ degs, int E) {
    int e = blockIdx.x * blockDim.x + threadIdx.x;
    if (e < E) { atomicAdd(&degd[dst[e]], 1); atomicAdd(&degs[src[e]], 1); }
}

// ---- deg_inv_sqrt (GCN norm uses in-degree by dst) ----
__global__ void dis_kernel(const int* __restrict__ degd, float* __restrict__ dis, int n) {
    int i = blockIdx.x * blockDim.x + threadIdx.x;
    if (i < n) {
        int d = degd[i];
        dis[i] = (d > 0) ? rsqrtf((float)d) : 0.0f;
    }
}

__device__ __forceinline__ int wave_incl_scan(int v, int lane) {
    #pragma unroll
    for (int off = 1; off < 64; off <<= 1) {
        int t = __shfl_up(v, off);
        if (lane >= off) v += t;
    }
    return v;
}

// ---- 3-stage exclusive scan of degs -> srow_ptr ----
__global__ __launch_bounds__(256) void scan_reduce(const int* __restrict__ deg,
                                                   int* __restrict__ bsum, int n) {
    __shared__ int wsum[4];
    int b = blockIdx.x, tid = threadIdx.x;
    int s = 0;
    for (int j = tid; j < 1024; j += 256) {
        int idx = b * 1024 + j;
        if (idx < n) s += deg[idx];
    }
    #pragma unroll
    for (int off = 32; off; off >>= 1) s += __shfl_down(s, off);
    int lane = tid & 63, wid = tid >> 6;
    if (lane == 0) wsum[wid] = s;
    __syncthreads();
    if (tid == 0) bsum[b] = wsum[0] + wsum[1] + wsum[2] + wsum[3];
}

__global__ void scan_bsum(const int* __restrict__ bsum, int* __restrict__ boff, int nb) {
    __shared__ int buf[1024];
    int tid = threadIdx.x;
    int v = (tid < nb) ? bsum[tid] : 0;
    buf[tid] = v;
    __syncthreads();
    for (int off = 1; off < 1024; off <<= 1) {
        int t = (tid >= off) ? buf[tid - off] : 0;
        __syncthreads();
        buf[tid] += t;
        __syncthreads();
    }
    if (tid < nb) boff[tid] = buf[tid] - v;
}

__global__ __launch_bounds__(256) void scan_final(const int* __restrict__ deg,
                                                  const int* __restrict__ boff,
                                                  int* __restrict__ row_ptr, int n) {
    __shared__ int wsum[4];
    int b = blockIdx.x, tid = threadIdx.x;
    int lane = tid & 63, wid = tid >> 6;
    int base = b * 1024 + tid * 4;
    int v[4], s = 0;
    #pragma unroll
    for (int j = 0; j < 4; j++) {
        int idx = base + j;
        v[j] = (idx < n) ? deg[idx] : 0;
        s += v[j];
    }
    int incl = wave_incl_scan(s, lane);
    if (lane == 63) wsum[wid] = incl;
    __syncthreads();
    int woff = 0;
    for (int w = 0; w < wid; w++) woff += wsum[w];
    int run = incl - s + woff + boff[b];
    #pragma unroll
    for (int j = 0; j < 4; j++) {
        int idx = base + j;
        run += v[j];
        if (idx < n) row_ptr[idx + 1] = run;
    }
    if (b == 0 && tid == 0) row_ptr[0] = 0;
}

// ---- CSR by SRC (for A^T application); neighbor = dst, weight = dis[src]*dis[dst] ----
__global__ void fill_csr_kernel(const int* __restrict__ src, const int* __restrict__ dst,
                                const float* __restrict__ dis, const int* __restrict__ srow,
                                int* __restrict__ cnt, int* __restrict__ scol,
                                float* __restrict__ senorm, int E) {
    int e = blockIdx.x * blockDim.x + threadIdx.x;
    if (e >= E) return;
    int s = src[e], d = dst[e];
    int pos = srow[s] + atomicAdd(&cnt[s], 1);
    scol[pos] = d;
    senorm[pos] = dis[s] * dis[d];
}

// ---- Y0 init: Y[sel_g, g] = 1 (auto-detect int32/int64 ptr) ----
__global__ void yinit_kernel(const int* __restrict__ ptr32, float* __restrict__ Y) {
    int g = threadIdx.x;   // one block of NG threads
    bool is64 = (ptr32[3] == 0);   // hi word of ptr[1] is 0 iff int64 (ptr[1] > 0)
    long long node;
    if (is64) node = ((const long long*)ptr32)[g + 1] - 1;
    else      node = (long long)ptr32[g + 1] - 1;
    Y[node * NG + g] = 1.0f;
}

// ---- Y_{k+1}[u,:] = sum_{e: src=u} norm_e * Y_k[dst_e,:]  (wave/node, 4-chain unroll) ----
__global__ __launch_bounds__(256) void spmm_kernel(const float* __restrict__ Yin,
                                                   const int* __restrict__ srow,
                                                   const int* __restrict__ scol,
                                                   const float* __restrict__ senorm,
                                                   float* __restrict__ Yout, int n) {
    int node = (blockIdx.x * blockDim.x + threadIdx.x) >> 6;
    int g = threadIdx.x & 63;
    if (node >= n) return;
    int beg = srow[node], end = srow[node + 1];
    float a0 = 0.f, a1 = 0.f, a2 = 0.f, a3 = 0.f;
    int j = beg;
    for (; j + 3 < end; j += 4) {
        int s0 = scol[j], s1 = scol[j + 1], s2 = scol[j + 2], s3 = scol[j + 3];
        float w0 = senorm[j], w1 = senorm[j + 1], w2 = senorm[j + 2], w3 = senorm[j + 3];
        a0 += Yin[(size_t)s0 * NG + g] * w0;
        a1 += Yin[(size_t)s1 * NG + g] * w1;
        a2 += Yin[(size_t)s2 * NG + g] * w2;
        a3 += Yin[(size_t)s3 * NG + g] * w3;
    }
    for (; j < end; j++) a0 += Yin[(size_t)scol[j] * NG + g] * senorm[j];
    Yout[(size_t)node * NG + g] = (a0 + a1) + (a2 + a3);
}

// ---- cs[g] += sum_i Y[i,g]  (= A^k 1 at selected nodes) ----
__global__ __launch_bounds__(256) void colsum_kernel(const float* __restrict__ Y,
                                                     float* __restrict__ cs, int n) {
    __shared__ float part[4][64];
    int g = threadIdx.x & 63, w = threadIdx.x >> 6;
    float a = 0.f;
    for (int i = blockIdx.x * 4 + w; i < n; i += gridDim.x * 4)
        a += Y[(size_t)i * NG + g];
    part[w][g] = a;
    __syncthreads();
    if (w == 0) atomicAdd(&cs[g], part[0][g] + part[1][g] + part[2][g] + part[3][g]);
}

// ---- zacc v3: Zp[b][g][d] = sum_{i in chunk b} Y[i,g] * emb[x[i],d]
// LDS-staged rank-1 updates; private per-block partials, no atomics. ----
__global__ __launch_bounds__(512, 4) void zacc_kernel(const float* __restrict__ Y,
                                                      const int* __restrict__ x,
                                                      const float* __restrict__ emb,
                                                      float* __restrict__ Zp, int n) {
    __shared__ float Yl[ZTILE * NG];        // 8 KB
    __shared__ float embl[ZTILE * D];       // 16 KB
    const float4* Y4 = (const float4*)Y;
    const float4* emb4 = (const float4*)emb;
    float4* Yl4 = (float4*)Yl;
    float4* embl4 = (float4*)embl;
    int tid = threadIdx.x;
    int g = tid & 63, d8 = tid >> 6;
    int i0 = blockIdx.x * ZCHUNK;
    float4 a0 = {0,0,0,0}, a1 = {0,0,0,0}, a2 = {0,0,0,0}, a3 = {0,0,0,0};
    for (int t = 0; t < ZCHUNK / ZTILE; t++) {
        int ib = i0 + t * ZTILE;
        // stage: thread -> (si = tid>>4, q = tid&15)
        int si = tid >> 4, q = tid & 15;
        int gi = ib + si;
        bool ok = (gi < n);
        float4 z4 = {0,0,0,0};
        Yl4[si * 16 + q] = ok ? Y4[(size_t)gi * 16 + q] : z4;     // coalesced: addr==tid
        int tok = ok ? x[gi] : 0;                                  // 16-thread broadcast
        embl4[si * 32 + q]      = emb4[(size_t)tok * 32 + q];      // 256B-chunk gather
        embl4[si * 32 + q + 16] = emb4[(size_t)tok * 32 + q + 16];
        __syncthreads();
        #pragma unroll 4
        for (int ii = 0; ii < ZTILE; ii++) {
            float y = Yl[ii * NG + g];                 // 2-way bank (free) / broadcast
            float4 e0 = embl4[ii * 32 + d8 * 4 + 0];   // wave-uniform -> broadcast
            float4 e1 = embl4[ii * 32 + d8 * 4 + 1];
            float4 e2 = embl4[ii * 32 + d8 * 4 + 2];
            float4 e3 = embl4[ii * 32 + d8 * 4 + 3];
            a0.x += y * e0.x; a0.y += y * e0.y; a0.z += y * e0.z; a0.w += y * e0.w;
            a1.x += y * e1.x; a1.y += y * e1.y; a1.z += y * e1.z; a1.w += y * e1.w;
            a2.x += y * e2.x; a2.y += y * e2.y; a2.z += y * e2.z; a2.w += y * e2.w;
            a3.x += y * e3.x; a3.y += y * e3.y; a3.z += y * e3.z; a3.w += y * e3.w;
        }
        __syncthreads();
    }
    float4* zp = (float4*)(Zp + (size_t)blockIdx.x * NG * D + g * D + d8 * 16);
    zp[0] = a0; zp[1] = a1; zp[2] = a2; zp[3] = a3;
}

// ---- zreduce v2: Z[o] += sum_{b in slice} Zp[b][o]
// grid (32 o-chunks, 8 b-slices) x 256 thr; 28 coalesced loads/thread; 8-way
// atomic per address (spread over 8192 addresses). Z pre-zeroed. ----
__global__ __launch_bounds__(256) void zreduce_kernel(const float* __restrict__ Zp,
                                                      float* __restrict__ Z, int nzb) {
    int o = blockIdx.x * blockDim.x + threadIdx.x;   // o < NG*D
    int bps = (nzb + gridDim.y - 1) / gridDim.y;
    int b0 = blockIdx.y * bps;
    int b1 = min(nzb, b0 + bps);
    float a = 0.f;
    #pragma unroll 4
    for (int b = b0; b < b1; b++) a += Zp[(size_t)b * NG * D + o];
    atomicAdd(&Z[o], a);
}

// ---- C = A*A for 128x128 (grid 16, block computes 8 rows; A staged in LDS) ----
__global__ __launch_bounds__(256) void matsq_kernel(const float* __restrict__ A,
                                                    float* __restrict__ C) {
    __shared__ float Al[D * D];
    int tid = threadIdx.x;
    const float4* A4 = (const float4*)A;
    float4* Al4 = (float4*)Al;
    for (int i = tid; i < D * D / 4; i += 256) Al4[i] = A4[i];
    __syncthreads();
    int r = blockIdx.x * 8 + (tid >> 5);
    int c0 = (tid & 31) * 4;
    float4 acc = {0.f, 0.f, 0.f, 0.f};
    for (int k = 0; k < D; k++) {
        float a = Al[r * D + k];
        float4 w = *(const float4*)&Al[k * D + c0];
        acc.x += a * w.x; acc.y += a * w.y; acc.z += a * w.z; acc.w += a * w.w;
    }
    *(float4*)&C[r * D + c0] = acc;
}

// ---- T[k] = b^T W^{k+1}, k=0..2 (one block, 128 threads) ----
__global__ void tvec_kernel(const float* __restrict__ b, const float* __restrict__ W,
                            float* __restrict__ T) {
    __shared__ float cur[D];
    int tid = threadIdx.x;
    cur[tid] = b[tid];
    __syncthreads();
    for (int it = 0; it < 3; it++) {
        float acc = 0.f;
        for (int k = 0; k < D; k++) acc += cur[k] * W[k * D + tid];
        __syncthreads();
        cur[tid] = acc;
        T[it * D + tid] = acc;
        __syncthreads();
    }
}

// ---- out[g,d] = (Z*W4)[g,d] + cs1[g]*T1[d] + cs2[g]*T2[d] + cs3[g]*T3[d] + b[d] ----
__global__ __launch_bounds__(256) void final_kernel(const float* __restrict__ Z,
                                                    const float* __restrict__ W4,
                                                    const float* __restrict__ T,
                                                    const float* __restrict__ cs,
                                                    const float* __restrict__ b,
                                                    float* __restrict__ out) {
    int o = blockIdx.x * blockDim.x + threadIdx.x;
    if (o >= NG * D) return;
    int g = o >> 7, d = o & (D - 1);
    float acc = b[d];
    for (int k = 0; k < D; k++) acc += Z[g * D + k] * W4[k * D + d];
    acc += cs[g] * T[d] + cs[64 + g] * T[D + d] + cs[128 + g] * T[2 * D + d];
    out[o] = acc;
}

extern "C" void kernel_launch(void* const* d_in, const int* in_sizes, int n_in,
                              void* d_out, int out_size, void* d_ws, size_t ws_size,
                              hipStream_t stream) {
    const int*   x    = (const int*)d_in[0];
    const int*   ei   = (const int*)d_in[1];
    const int*   ptr  = (const int*)d_in[2];   // width auto-detected on device
    const float* emb  = (const float*)d_in[4];
    const float* W    = (const float*)d_in[5];
    const float* bias = (const float*)d_in[6];

    const int N = in_sizes[0];
    const int E = in_sizes[1] / 2;

    const int* src = ei;
    const int* dst = ei + E;

    char* ws = (char*)d_ws;
    size_t off = 0;
    auto carve = [&](size_t bytes) -> void* {
        void* p = ws + off;
        off += (bytes + 255) & ~(size_t)255;
        return p;
    };
    float* Ya     = (float*)carve((size_t)N * NG * 4);
    float* Yb     = (float*)carve((size_t)N * NG * 4);
    int*   degd   = (int*)  carve((size_t)N * 4 * 2);   // degd + degs adjacent (one memset)
    int*   degs   = degd + N;
    float* dis    = (float*)carve((size_t)N * 4);
    int*   srow   = (int*)  carve((size_t)(N + 1) * 4);
    int*   cnt    = (int*)  carve((size_t)N * 4);
    int*   scol   = (int*)  carve((size_t)E * 4);
    float* senorm = (float*)carve((size_t)E * 4);
    int    nb     = (N + 1023) / 1024;
    int*   bsum   = (int*)  carve((size_t)nb * 4);
    int*   boff   = (int*)  carve((size_t)nb * 4);
    float* Z      = (float*)carve((size_t)NG * D * 4);  // 32768 B, 256-aligned
    float* cs     = (float*)carve((size_t)3 * NG * 4);  // adjacent to Z
    float* W2     = (float*)carve((size_t)D * D * 4);
    float* W4     = (float*)carve((size_t)D * D * 4);
    float* T      = (float*)carve((size_t)3 * D * 4);
    int    nzb    = (N + ZCHUNK - 1) / ZCHUNK;
    float* Zp     = (float*)carve((size_t)nzb * NG * D * 4);  // ~7.3 MB partials

    hipMemsetAsync(degd, 0, (size_t)N * 4 * 2, stream);
    hipMemsetAsync(cnt,  0, (size_t)N * 4, stream);
    hipMemsetAsync(Ya,   0, (size_t)N * NG * 4, stream);
    hipMemsetAsync(Z,    0, (size_t)(NG * D + 3 * NG) * 4, stream);  // Z + cs contiguous

    hist2_kernel<<<(E + 255) / 256, 256, 0, stream>>>(src, dst, degd, degs, E);
    dis_kernel<<<(N + 255) / 256, 256, 0, stream>>>(degd, dis, N);
    scan_reduce<<<nb, 256, 0, stream>>>(degs, bsum, N);
    scan_bsum<<<1, 1024, 0, stream>>>(bsum, boff, nb);
    scan_final<<<nb, 256, 0, stream>>>(degs, boff, srow, N);
    fill_csr_kernel<<<(E + 255) / 256, 256, 0, stream>>>(src, dst, dis, srow, cnt,
                                                         scol, senorm, E);
    yinit_kernel<<<1, NG, 0, stream>>>(ptr, Ya);

    int sg = (N * 64 + 255) / 256;
    spmm_kernel<<<sg, 256, 0, stream>>>(Ya, srow, scol, senorm, Yb, N);   // Y1
    colsum_kernel<<<64, 256, 0, stream>>>(Yb, cs + 0, N);
    spmm_kernel<<<sg, 256, 0, stream>>>(Yb, srow, scol, senorm, Ya, N);   // Y2
    colsum_kernel<<<64, 256, 0, stream>>>(Ya, cs + 64, N);
    spmm_kernel<<<sg, 256, 0, stream>>>(Ya, srow, scol, senorm, Yb, N);   // Y3
    colsum_kernel<<<64, 256, 0, stream>>>(Yb, cs + 128, N);
    spmm_kernel<<<sg, 256, 0, stream>>>(Yb, srow, scol, senorm, Ya, N);   // Y4

    matsq_kernel<<<16, 256, 0, stream>>>(W, W2);
    matsq_kernel<<<16, 256, 0, stream>>>(W2, W4);
    tvec_kernel<<<1, D, 0, stream>>>(bias, W, T);

    zacc_kernel<<<nzb, 512, 0, stream>>>(Ya, x, emb, Zp, N);
    dim3 zrgrid(32, 8);
    zreduce_kernel<<<zrgrid, 256, 0, stream>>>(Zp, Z, nzb);
    final_kernel<<<(NG * D + 255) / 256, 256, 0, stream>>>(Z, W4, T, cs, bias,
                                                           (float*)d_out);
}

// Round 17
// 444.077 us; speedup vs baseline: 1.8144x; 1.1321x over previous
//
#include <hip/hip_runtime.h>
#include <hip/hip_bf16.h>

// GCN encoder, reassociated:  out = Y4^T · emb[x] · W^4 + bias terms.
// R15: top-5 = colsum 50us x3 @2.4% occupancy (tiny-grid latency, 4th instance) and
// hist2 50us with WRITE 37MB for a 400KB histogram (cross-XCD atomic line-bounce).
// R17: (a) colsum grid 64->1024 [launch-config only, zero risk];
//      (b) hist2 v2 = 8-way XCD-privatized partial histograms (c = blockIdx&7 ->
//          atomics stay in one XCD's L2) + histreduce sum. degd/degs memset dropped,
//          degp (3.2MB) memset added.

#define D 128
#define NG 64     // graphs in batch (B)
#define ZTILE 32  // i's per LDS tile in zacc
#define ZCHUNK 224 // i's per zacc block (7 tiles)

// ---- hist2 v2: 8-way privatized degree histograms ----
// degp layout: copies 0..7 = degd partials (c*N + node), copies 8..15 = degs partials.
__global__ void hist2_kernel(const int* __restrict__ src, const int* __restrict__ dst,
                             int* __restrict__ degp, int E, int N) {
    int e = blockIdx.x * blockDim.x + threadIdx.x;
    int c = blockIdx.x & 7;          // ~XCD id under round-robin dispatch (perf-only)
    if (e < E) {
        atomicAdd(&degp[(size_t)c * N + dst[e]], 1);
        atomicAdd(&degp[(size_t)(8 + c) * N + src[e]], 1);
    }
}

// ---- degd[i] = sum_c degp[c][i]; degs[i] = sum_c degp[8+c][i] ----
__global__ __launch_bounds__(256) void histreduce_kernel(const int* __restrict__ degp,
                                                         int* __restrict__ degd,
                                                         int* __restrict__ degs, int N) {
    int i = blockIdx.x * blockDim.x + threadIdx.x;
    if (i >= N) return;
    int a = 0, b = 0;
    #pragma unroll
    for (int c = 0; c < 8; c++) {
        a += degp[(size_t)c * N + i];
        b += degp[(size_t)(8 + c) * N + i];
    }
    degd[i] = a;
    degs[i] = b;
}

// ---- deg_inv_sqrt (GCN norm uses in-degree by dst) ----
__global__ void dis_kernel(const int* __restrict__ degd, float* __restrict__ dis, int n) {
    int i = blockIdx.x * blockDim.x + threadIdx.x;
    if (i < n) {
        int d = degd[i];
        dis[i] = (d > 0) ? rsqrtf((float)d) : 0.0f;
    }
}

__device__ __forceinline__ int wave_incl_scan(int v, int lane) {
    #pragma unroll
    for (int off = 1; off < 64; off <<= 1) {
        int t = __shfl_up(v, off);
        if (lane >= off) v += t;
    }
    return v;
}

// ---- 3-stage exclusive scan of degs -> srow_ptr ----
__global__ __launch_bounds__(256) void scan_reduce(const int* __restrict__ deg,
                                                   int* __restrict__ bsum, int n) {
    __shared__ int wsum[4];
    int b = blockIdx.x, tid = threadIdx.x;
    int s = 0;
    for (int j = tid; j < 1024; j += 256) {
        int idx = b * 1024 + j;
        if (idx < n) s += deg[idx];
    }
    #pragma unroll
    for (int off = 32; off; off >>= 1) s += __shfl_down(s, off);
    int lane = tid & 63, wid = tid >> 6;
    if (lane == 0) wsum[wid] = s;
    __syncthreads();
    if (tid == 0) bsum[b] = wsum[0] + wsum[1] + wsum[2] + wsum[3];
}

__global__ void scan_bsum(const int* __restrict__ bsum, int* __restrict__ boff, int nb) {
    __shared__ int buf[1024];
    int tid = threadIdx.x;
    int v = (tid < nb) ? bsum[tid] : 0;
    buf[tid] = v;
    __syncthreads();
    for (int off = 1; off < 1024; off <<= 1) {
        int t = (tid >= off) ? buf[tid - off] : 0;
        __syncthreads();
        buf[tid] += t;
        __syncthreads();
    }
    if (tid < nb) boff[tid] = buf[tid] - v;
}

__global__ __launch_bounds__(256) void scan_final(const int* __restrict__ deg,
                                                  const int* __restrict__ boff,
                                                  int* __restrict__ row_ptr, int n) {
    __shared__ int wsum[4];
    int b = blockIdx.x, tid = threadIdx.x;
    int lane = tid & 63, wid = tid >> 6;
    int base = b * 1024 + tid * 4;
    int v[4], s = 0;
    #pragma unroll
    for (int j = 0; j < 4; j++) {
        int idx = base + j;
        v[j] = (idx < n) ? deg[idx] : 0;
        s += v[j];
    }
    int incl = wave_incl_scan(s, lane);
    if (lane == 63) wsum[wid] = incl;
    __syncthreads();
    int woff = 0;
    for (int w = 0; w < wid; w++) woff += wsum[w];
    int run = incl - s + woff + boff[b];
    #pragma unroll
    for (int j = 0; j < 4; j++) {
        int idx = base + j;
        run += v[j];
        if (idx < n) row_ptr[idx + 1] = run;
    }
    if (b == 0 && tid == 0) row_ptr[0] = 0;
}

// ---- CSR by SRC (for A^T application); neighbor = dst, weight = dis[src]*dis[dst] ----
__global__ void fill_csr_kernel(const int* __restrict__ src, const int* __restrict__ dst,
                                const float* __restrict__ dis, const int* __restrict__ srow,
                                int* __restrict__ cnt, int* __restrict__ scol,
                                float* __restrict__ senorm, int E) {
    int e = blockIdx.x * blockDim.x + threadIdx.x;
    if (e >= E) return;
    int s = src[e], d = dst[e];
    int pos = srow[s] + atomicAdd(&cnt[s], 1);
    scol[pos] = d;
    senorm[pos] = dis[s] * dis[d];
}

// ---- Y0 init: Y[sel_g, g] = 1 (auto-detect int32/int64 ptr) ----
__global__ void yinit_kernel(const int* __restrict__ ptr32, float* __restrict__ Y) {
    int g = threadIdx.x;   // one block of NG threads
    bool is64 = (ptr32[3] == 0);   // hi word of ptr[1] is 0 iff int64 (ptr[1] > 0)
    long long node;
    if (is64) node = ((const long long*)ptr32)[g + 1] - 1;
    else      node = (long long)ptr32[g + 1] - 1;
    Y[node * NG + g] = 1.0f;
}

// ---- Y_{k+1}[u,:] = sum_{e: src=u} norm_e * Y_k[dst_e,:]  (wave/node, 4-chain unroll) ----
__global__ __launch_bounds__(256) void spmm_kernel(const float* __restrict__ Yin,
                                                   const int* __restrict__ srow,
                                                   const int* __restrict__ scol,
                                                   const float* __restrict__ senorm,
                                                   float* __restrict__ Yout, int n) {
    int node = (blockIdx.x * blockDim.x + threadIdx.x) >> 6;
    int g = threadIdx.x & 63;
    if (node >= n) return;
    int beg = srow[node], end = srow[node + 1];
    float a0 = 0.f, a1 = 0.f, a2 = 0.f, a3 = 0.f;
    int j = beg;
    for (; j + 3 < end; j += 4) {
        int s0 = scol[j], s1 = scol[j + 1], s2 = scol[j + 2], s3 = scol[j + 3];
        float w0 = senorm[j], w1 = senorm[j + 1], w2 = senorm[j + 2], w3 = senorm[j + 3];
        a0 += Yin[(size_t)s0 * NG + g] * w0;
        a1 += Yin[(size_t)s1 * NG + g] * w1;
        a2 += Yin[(size_t)s2 * NG + g] * w2;
        a3 += Yin[(size_t)s3 * NG + g] * w3;
    }
    for (; j < end; j++) a0 += Yin[(size_t)scol[j] * NG + g] * senorm[j];
    Yout[(size_t)node * NG + g] = (a0 + a1) + (a2 + a3);
}

// ---- cs[g] += sum_i Y[i,g]; launched with 1024 blocks (R16/R17 fix) ----
__global__ __launch_bounds__(256) void colsum_kernel(const float* __restrict__ Y,
                                                     float* __restrict__ cs, int n) {
    __shared__ float part[4][64];
    int g = threadIdx.x & 63, w = threadIdx.x >> 6;
    float a = 0.f;
    for (int i = blockIdx.x * 4 + w; i < n; i += gridDim.x * 4)
        a += Y[(size_t)i * NG + g];
    part[w][g] = a;
    __syncthreads();
    if (w == 0) atomicAdd(&cs[g], part[0][g] + part[1][g] + part[2][g] + part[3][g]);
}

// ---- zacc v3: Zp[b][g][d] = sum_{i in chunk b} Y[i,g] * emb[x[i],d]
// LDS-staged rank-1 updates; private per-block partials, no atomics. ----
__global__ __launch_bounds__(512, 4) void zacc_kernel(const float* __restrict__ Y,
                                                      const int* __restrict__ x,
                                                      const float* __restrict__ emb,
                                                      float* __restrict__ Zp, int n) {
    __shared__ float Yl[ZTILE * NG];        // 8 KB
    __shared__ float embl[ZTILE * D];       // 16 KB
    const float4* Y4 = (const float4*)Y;
    const float4* emb4 = (const float4*)emb;
    float4* Yl4 = (float4*)Yl;
    float4* embl4 = (float4*)embl;
    int tid = threadIdx.x;
    int g = tid & 63, d8 = tid >> 6;
    int i0 = blockIdx.x * ZCHUNK;
    float4 a0 = {0,0,0,0}, a1 = {0,0,0,0}, a2 = {0,0,0,0}, a3 = {0,0,0,0};
    for (int t = 0; t < ZCHUNK / ZTILE; t++) {
        int ib = i0 + t * ZTILE;
        int si = tid >> 4, q = tid & 15;
        int gi = ib + si;
        bool ok = (gi < n);
        float4 z4 = {0,0,0,0};
        Yl4[si * 16 + q] = ok ? Y4[(size_t)gi * 16 + q] : z4;     // coalesced: addr==tid
        int tok = ok ? x[gi] : 0;                                  // 16-thread broadcast
        embl4[si * 32 + q]      = emb4[(size_t)tok * 32 + q];      // 256B-chunk gather
        embl4[si * 32 + q + 16] = emb4[(size_t)tok * 32 + q + 16];
        __syncthreads();
        #pragma unroll 4
        for (int ii = 0; ii < ZTILE; ii++) {
            float y = Yl[ii * NG + g];                 // 2-way bank (free) / broadcast
            float4 e0 = embl4[ii * 32 + d8 * 4 + 0];   // wave-uniform -> broadcast
            float4 e1 = embl4[ii * 32 + d8 * 4 + 1];
            float4 e2 = embl4[ii * 32 + d8 * 4 + 2];
            float4 e3 = embl4[ii * 32 + d8 * 4 + 3];
            a0.x += y * e0.x; a0.y += y * e0.y; a0.z += y * e0.z; a0.w += y * e0.w;
            a1.x += y * e1.x; a1.y += y * e1.y; a1.z += y * e1.z; a1.w += y * e1.w;
            a2.x += y * e2.x; a2.y += y * e2.y; a2.z += y * e2.z; a2.w += y * e2.w;
            a3.x += y * e3.x; a3.y += y * e3.y; a3.z += y * e3.z; a3.w += y * e3.w;
        }
        __syncthreads();
    }
    float4* zp = (float4*)(Zp + (size_t)blockIdx.x * NG * D + g * D + d8 * 16);
    zp[0] = a0; zp[1] = a1; zp[2] = a2; zp[3] = a3;
}

// ---- zreduce v2: Z[o] += sum_{b in slice} Zp[b][o] ----
__global__ __launch_bounds__(256) void zreduce_kernel(const float* __restrict__ Zp,
                                                      float* __restrict__ Z, int nzb) {
    int o = blockIdx.x * blockDim.x + threadIdx.x;   // o < NG*D
    int bps = (nzb + gridDim.y - 1) / gridDim.y;
    int b0 = blockIdx.y * bps;
    int b1 = min(nzb, b0 + bps);
    float a = 0.f;
    #pragma unroll 4
    for (int b = b0; b < b1; b++) a += Zp[(size_t)b * NG * D + o];
    atomicAdd(&Z[o], a);
}

// ---- C = A*A for 128x128 (grid 16, block computes 8 rows; A staged in LDS) ----
__global__ __launch_bounds__(256) void matsq_kernel(const float* __restrict__ A,
                                                    float* __restrict__ C) {
    __shared__ float Al[D * D];
    int tid = threadIdx.x;
    const float4* A4 = (const float4*)A;
    float4* Al4 = (float4*)Al;
    for (int i = tid; i < D * D / 4; i += 256) Al4[i] = A4[i];
    __syncthreads();
    int r = blockIdx.x * 8 + (tid >> 5);
    int c0 = (tid & 31) * 4;
    float4 acc = {0.f, 0.f, 0.f, 0.f};
    for (int k = 0; k < D; k++) {
        float a = Al[r * D + k];
        float4 w = *(const float4*)&Al[k * D + c0];
        acc.x += a * w.x; acc.y += a * w.y; acc.z += a * w.z; acc.w += a * w.w;
    }
    *(float4*)&C[r * D + c0] = acc;
}

// ---- T[k] = b^T W^{k+1}, k=0..2 (one block, 128 threads) ----
__global__ void tvec_kernel(const float* __restrict__ b, const float* __restrict__ W,
                            float* __restrict__ T) {
    __shared__ float cur[D];
    int tid = threadIdx.x;
    cur[tid] = b[tid];
    __syncthreads();
    for (int it = 0; it < 3; it++) {
        float acc = 0.f;
        for (int k = 0; k < D; k++) acc += cur[k] * W[k * D + tid];
        __syncthreads();
        cur[tid] = acc;
        T[it * D + tid] = acc;
        __syncthreads();
    }
}

// ---- out[g,d] = (Z*W4)[g,d] + cs1[g]*T1[d] + cs2[g]*T2[d] + cs3[g]*T3[d] + b[d] ----
__global__ __launch_bounds__(256) void final_kernel(const float* __restrict__ Z,
                                                    const float* __restrict__ W4,
                                                    const float* __restrict__ T,
                                                    const float* __restrict__ cs,
                                                    const float* __restrict__ b,
                                                    float* __restrict__ out) {
    int o = blockIdx.x * blockDim.x + threadIdx.x;
    if (o >= NG * D) return;
    int g = o >> 7, d = o & (D - 1);
    float acc = b[d];
    for (int k = 0; k < D; k++) acc += Z[g * D + k] * W4[k * D + d];
    acc += cs[g] * T[d] + cs[64 + g] * T[D + d] + cs[128 + g] * T[2 * D + d];
    out[o] = acc;
}

extern "C" void kernel_launch(void* const* d_in, const int* in_sizes, int n_in,
                              void* d_out, int out_size, void* d_ws, size_t ws_size,
                              hipStream_t stream) {
    const int*   x    = (const int*)d_in[0];
    const int*   ei   = (const int*)d_in[1];
    const int*   ptr  = (const int*)d_in[2];   // width auto-detected on device
    const float* emb  = (const float*)d_in[4];
    const float* W    = (const float*)d_in[5];
    const float* bias = (const float*)d_in[6];

    const int N = in_sizes[0];
    const int E = in_sizes[1] / 2;

    const int* src = ei;
    const int* dst = ei + E;

    char* ws = (char*)d_ws;
    size_t off = 0;
    auto carve = [&](size_t bytes) -> void* {
        void* p = ws + off;
        off += (bytes + 255) & ~(size_t)255;
        return p;
    };
    float* Ya     = (float*)carve((size_t)N * NG * 4);
    float* Yb     = (float*)carve((size_t)N * NG * 4);
    int*   degd   = (int*)  carve((size_t)N * 4);
    int*   degs   = (int*)  carve((size_t)N * 4);
    int*   degp   = (int*)  carve((size_t)16 * N * 4);  // 8 copies x {degd,degs}, 3.2MB
    float* dis    = (float*)carve((size_t)N * 4);
    int*   srow   = (int*)  carve((size_t)(N + 1) * 4);
    int*   cnt    = (int*)  carve((size_t)N * 4);
    int*   scol   = (int*)  carve((size_t)E * 4);
    float* senorm = (float*)carve((size_t)E * 4);
    int    nb     = (N + 1023) / 1024;
    int*   bsum   = (int*)  carve((size_t)nb * 4);
    int*   boff   = (int*)  carve((size_t)nb * 4);
    float* Z      = (float*)carve((size_t)NG * D * 4);  // 32768 B, 256-aligned
    float* cs     = (float*)carve((size_t)3 * NG * 4);  // adjacent to Z
    float* W2     = (float*)carve((size_t)D * D * 4);
    float* W4     = (float*)carve((size_t)D * D * 4);
    float* T      = (float*)carve((size_t)3 * D * 4);
    int    nzb    = (N + ZCHUNK - 1) / ZCHUNK;
    float* Zp     = (float*)carve((size_t)nzb * NG * D * 4);  // ~7.3 MB partials

    hipMemsetAsync(degp, 0, (size_t)16 * N * 4, stream);
    hipMemsetAsync(cnt,  0, (size_t)N * 4, stream);
    hipMemsetAsync(Ya,   0, (size_t)N * NG * 4, stream);
    hipMemsetAsync(Z,    0, (size_t)(NG * D + 3 * NG) * 4, stream);  // Z + cs contiguous

    hist2_kernel<<<(E + 255) / 256, 256, 0, stream>>>(src, dst, degp, E, N);
    histreduce_kernel<<<(N + 255) / 256, 256, 0, stream>>>(degp, degd, degs, N);
    dis_kernel<<<(N + 255) / 256, 256, 0, stream>>>(degd, dis, N);
    scan_reduce<<<nb, 256, 0, stream>>>(degs, bsum, N);
    scan_bsum<<<1, 1024, 0, stream>>>(bsum, boff, nb);
    scan_final<<<nb, 256, 0, stream>>>(degs, boff, srow, N);
    fill_csr_kernel<<<(E + 255) / 256, 256, 0, stream>>>(src, dst, dis, srow, cnt,
                                                         scol, senorm, E);
    yinit_kernel<<<1, NG, 0, stream>>>(ptr, Ya);

    int sg = (N * 64 + 255) / 256;
    spmm_kernel<<<sg, 256, 0, stream>>>(Ya, srow, scol, senorm, Yb, N);   // Y1
    colsum_kernel<<<1024, 256, 0, stream>>>(Yb, cs + 0, N);
    spmm_kernel<<<sg, 256, 0, stream>>>(Yb, srow, scol, senorm, Ya, N);   // Y2
    colsum_kernel<<<1024, 256, 0, stream>>>(Ya, cs + 64, N);
    spmm_kernel<<<sg, 256, 0, stream>>>(Ya, srow, scol, senorm, Yb, N);   // Y3
    colsum_kernel<<<1024, 256, 0, stream>>>(Yb, cs + 128, N);
    spmm_kernel<<<sg, 256, 0, stream>>>(Yb, srow, scol, senorm, Ya, N);   // Y4

    matsq_kernel<<<16, 256, 0, stream>>>(W, W2);
    matsq_kernel<<<16, 256, 0, stream>>>(W2, W4);
    tvec_kernel<<<1, D, 0, stream>>>(bias, W, T);

    zacc_kernel<<<nzb, 512, 0, stream>>>(Ya, x, emb, Zp, N);
    dim3 zrgrid(32, 8);
    zreduce_kernel<<<zrgrid, 256, 0, stream>>>(Zp, Z, nzb);
    final_kernel<<<(NG * D + 255) / 256, 256, 0, stream>>>(Z, W4, T, cs, bias,
                                                           (float*)d_out);
}